// Round 1
// baseline (410.012 us; speedup 1.0000x reference)
//
#include <hip/hip_runtime.h>
#include <hip/hip_bf16.h>
#include <stdint.h>

// Problem constants (B=8192, H=1024, E=8, K=2)
#define B_TOK 8192
#define H_DIM 1024
#define E_NUM 8

typedef __attribute__((ext_vector_type(8))) short short8;   // 8 bf16 = 4 VGPRs (MFMA A/B frag)
typedef __attribute__((ext_vector_type(4))) float floatx4;  // MFMA C/D frag

__device__ __forceinline__ unsigned short f32_to_bf16_rne(float f) {
  union { float f; uint32_t u; } v; v.f = f;
  uint32_t u = v.u;
  uint32_t r = u + 0x7FFFu + ((u >> 16) & 1u);  // round-to-nearest-even; inputs finite
  return (unsigned short)(r >> 16);
}

// ---------------- x fp32 -> bf16 ----------------
__global__ __launch_bounds__(256) void convert_x_kernel(const float* __restrict__ x,
                                                        unsigned short* __restrict__ xb) {
  int i = (blockIdx.x * 256 + threadIdx.x) * 4;
  float4 v = *(const float4*)(x + i);
  ushort4 o;
  o.x = f32_to_bf16_rne(v.x);
  o.y = f32_to_bf16_rne(v.y);
  o.z = f32_to_bf16_rne(v.z);
  o.w = f32_to_bf16_rne(v.w);
  *(ushort4*)(xb + i) = o;
}

// ---------- expert_w [e][k][n] fp32 -> Wt [e][n][k] bf16 (transpose last 2 dims) ----------
__global__ __launch_bounds__(256) void transpose_w_kernel(const float* __restrict__ w,
                                                          unsigned short* __restrict__ wt) {
  __shared__ float tile[32][33];
  int e = blockIdx.z;
  int n0 = blockIdx.x * 32, k0 = blockIdx.y * 32;
  int tx = threadIdx.x, ty = threadIdx.y;  // (32, 8)
  const float* wb = w + (size_t)e * H_DIM * H_DIM;
  unsigned short* wtb = wt + (size_t)e * H_DIM * H_DIM;
#pragma unroll
  for (int j = 0; j < 4; j++) {
    int r = ty + j * 8;
    tile[r][tx] = wb[(size_t)(k0 + r) * H_DIM + n0 + tx];  // coalesced over n
  }
  __syncthreads();
#pragma unroll
  for (int j = 0; j < 4; j++) {
    int r = ty + j * 8;
    wtb[(size_t)(n0 + r) * H_DIM + k0 + tx] = f32_to_bf16_rne(tile[tx][r]);  // coalesced over k
  }
}

// ---------------- gate: fp32 logits, top-2, softmax, per-expert compaction ----------------
__global__ __launch_bounds__(256) void gate_kernel(const float* __restrict__ x,
                                                   const float* __restrict__ gw,
                                                   int* __restrict__ cnt,
                                                   int* __restrict__ slot_tok,
                                                   float* __restrict__ slot_w) {
  __shared__ float gws[E_NUM * H_DIM];  // [e][h] layout -> conflict-free lane reads
  int tid = threadIdx.x;
  for (int i = tid; i < E_NUM * H_DIM; i += 256) {
    int h = i >> 3, e = i & 7;
    gws[e * H_DIM + h] = gw[i];  // gw is [h][e] row-major
  }
  __syncthreads();
  int wid = tid >> 6, lane = tid & 63;
  int b = blockIdx.x * 4 + wid;  // one token per wave
  float acc[E_NUM];
#pragma unroll
  for (int e = 0; e < E_NUM; e++) acc[e] = 0.f;
  const float* xr = x + (size_t)b * H_DIM;
#pragma unroll 4
  for (int i = 0; i < 16; i++) {
    int h = i * 64 + lane;
    float xv = xr[h];
#pragma unroll
    for (int e = 0; e < E_NUM; e++) acc[e] += xv * gws[e * H_DIM + h];
  }
#pragma unroll
  for (int e = 0; e < E_NUM; e++) {
#pragma unroll
    for (int off = 32; off; off >>= 1) acc[e] += __shfl_xor(acc[e], off, 64);
  }
  if (lane == 0) {
    int e0 = 0; float v0 = acc[0];
#pragma unroll
    for (int e = 1; e < E_NUM; e++) if (acc[e] > v0) { v0 = acc[e]; e0 = e; }
    int e1 = -1; float v1 = -1e30f;
#pragma unroll
    for (int e = 0; e < E_NUM; e++) if (e != e0 && acc[e] > v1) { v1 = acc[e]; e1 = e; }
    float t = expf(v1 - v0);
    float w0 = 1.0f / (1.0f + t);
    float w1 = t * w0;
    int p0 = atomicAdd(&cnt[e0], 1);
    slot_tok[e0 * B_TOK + p0] = b;
    slot_w[e0 * B_TOK + p0] = w0;
    int p1 = atomicAdd(&cnt[e1], 1);
    slot_tok[e1 * B_TOK + p1] = b;
    slot_w[e1 * B_TOK + p1] = w1;
  }
}

// ---------------- grouped gather-GEMM: per expert, gathered rows of x @ W_e ----------------
// Tile 128x128, BK=32, 4 waves (2x2 of 64x64), mfma_f32_16x16x32_bf16, global_load_lds x16.
__device__ __forceinline__ void async_ld16(const void* g, void* l) {
  __builtin_amdgcn_global_load_lds((const __attribute__((address_space(1))) void*)g,
                                   (__attribute__((address_space(3))) void*)l, 16, 0, 0);
}

__global__ __launch_bounds__(256, 2) void moe_gemm_kernel(
    const unsigned short* __restrict__ xb,   // bf16 [B][H]
    const unsigned short* __restrict__ wt,   // bf16 [E][n][k]
    const int* __restrict__ cnt,             // [E]
    const int* __restrict__ slot_tok,        // [E][B]
    const float* __restrict__ slot_w,        // [E][B]
    float* __restrict__ out) {               // fp32 [B][H], pre-zeroed
  int e = blockIdx.z;
  int c = cnt[e];
  int m0 = blockIdx.y * 128;
  if (m0 >= c) return;
  int n0 = blockIdx.x * 128;

  __shared__ __align__(16) unsigned short As[128 * 32];  // [row][k], 64B rows
  __shared__ __align__(16) unsigned short Bs[128 * 32];  // [n][k]

  int tid = threadIdx.x, wid = tid >> 6, lane = tid & 63;
  // staging: each wave loads 16 rows x 64B per issue; lane -> (row, 16B chunk)
  int rs = wid * 16 + (lane >> 2);   // 0..63
  int kc = (lane & 3) * 8;           // bf16 col offset
  const int* st = slot_tok + e * B_TOK;
  const float* sw = slot_w + e * B_TOK;
  int ra1 = min(m0 + rs, c - 1);          // clamp tail rows (weight-0 at epilogue)
  int ra2 = min(m0 + 64 + rs, c - 1);
  const unsigned short* gA1 = xb + (size_t)st[ra1] * H_DIM + kc;
  const unsigned short* gA2 = xb + (size_t)st[ra2] * H_DIM + kc;
  const unsigned short* gB1 = wt + ((size_t)e * H_DIM + n0 + rs) * H_DIM + kc;
  const unsigned short* gB2 = wt + ((size_t)e * H_DIM + n0 + 64 + rs) * H_DIM + kc;
  unsigned short* lA1 = As + wid * 512;          // rows wid*16..+15
  unsigned short* lA2 = As + 2048 + wid * 512;   // rows 64+wid*16..+15
  unsigned short* lB1 = Bs + wid * 512;
  unsigned short* lB2 = Bs + 2048 + wid * 512;

  floatx4 acc[4][4];
#pragma unroll
  for (int a = 0; a < 4; ++a)
#pragma unroll
    for (int b = 0; b < 4; ++b)
#pragma unroll
      for (int q = 0; q < 4; ++q) acc[a][b][q] = 0.0f;

  int wm = (wid >> 1) * 64, wn = (wid & 1) * 64;
  int mr = lane & 15, kg = lane >> 4;  // A/B frag: row=lane&15, k-group=lane>>4

  for (int ks = 0; ks < H_DIM / 32; ++ks) {
    __syncthreads();  // previous tile fully consumed
    async_ld16(gA1, lA1);
    async_ld16(gA2, lA2);
    async_ld16(gB1, lB1);
    async_ld16(gB2, lB2);
    gA1 += 32; gA2 += 32; gB1 += 32; gB2 += 32;
    __syncthreads();  // drains vmcnt -> LDS tile visible
    short8 af[4], bfr[4];
#pragma unroll
    for (int t = 0; t < 4; ++t) {
      af[t] = *(const short8*)(const void*)(As + (wm + t * 16 + mr) * 32 + kg * 8);
      bfr[t] = *(const short8*)(const void*)(Bs + (wn + t * 16 + mr) * 32 + kg * 8);
    }
#pragma unroll
    for (int tm = 0; tm < 4; ++tm)
#pragma unroll
      for (int tn = 0; tn < 4; ++tn)
        acc[tm][tn] = __builtin_amdgcn_mfma_f32_16x16x32_bf16(af[tm], bfr[tn], acc[tm][tn], 0, 0, 0);
  }

  // epilogue: out[tok][n] += w_row * acc ; C/D layout: col=lane&15, row=kg*4+q
#pragma unroll
  for (int tm = 0; tm < 4; ++tm) {
#pragma unroll
    for (int q = 0; q < 4; ++q) {
      int r = m0 + wm + tm * 16 + kg * 4 + q;
      if (r < c) {
        int tok = st[r];
        float w = sw[r];
        float* orow = out + (size_t)tok * H_DIM + n0 + wn + mr;
#pragma unroll
        for (int tn = 0; tn < 4; ++tn) atomicAdd(orow + tn * 16, w * acc[tm][tn][q]);
      }
    }
  }
}

extern "C" void kernel_launch(void* const* d_in, const int* in_sizes, int n_in,
                              void* d_out, int out_size, void* d_ws, size_t ws_size,
                              hipStream_t stream) {
  const float* x  = (const float*)d_in[0];   // [8192][1024]
  const float* gw = (const float*)d_in[1];   // [1024][8]
  const float* ew = (const float*)d_in[2];   // [8][1024][1024]
  float* out = (float*)d_out;                // [8192][1024]

  char* ws = (char*)d_ws;
  unsigned short* xb = (unsigned short*)ws;                              // 16 MiB
  unsigned short* wt = (unsigned short*)(ws + (size_t)16 * 1024 * 1024); // 16 MiB
  char* p32 = ws + (size_t)32 * 1024 * 1024;
  int* cnt      = (int*)p32;                          // 32 B (pad 4 KiB)
  int* slot_tok = (int*)(p32 + 4096);                 // 256 KiB
  float* slot_w = (float*)(p32 + 4096 + (size_t)E_NUM * B_TOK * 4);  // 256 KiB

  hipMemsetAsync(out, 0, (size_t)B_TOK * H_DIM * sizeof(float), stream);
  hipMemsetAsync(cnt, 0, 64, stream);
  convert_x_kernel<<<B_TOK * H_DIM / (256 * 4), 256, 0, stream>>>(x, xb);
  transpose_w_kernel<<<dim3(32, 32, E_NUM), dim3(32, 8), 0, stream>>>(ew, wt);
  gate_kernel<<<B_TOK / 4, 256, 0, stream>>>(x, gw, cnt, slot_tok, slot_w);
  moe_gemm_kernel<<<dim3(H_DIM / 128, B_TOK / 128, E_NUM), 256, 0, stream>>>(
      xb, wt, cnt, slot_tok, slot_w, out);
}

// Round 2
// 194.243 us; speedup vs baseline: 2.1108x; 2.1108x over previous
//
#include <hip/hip_runtime.h>
#include <hip/hip_bf16.h>
#include <stdint.h>

// Problem constants (B=8192, H=1024, E=8, K=2)
#define B_TOK 8192
#define H_DIM 1024
#define E_NUM 8
#define NSLOT (2 * B_TOK)

typedef __attribute__((ext_vector_type(8))) short short8;   // 8 bf16 = 4 VGPRs (MFMA A/B frag)
typedef __attribute__((ext_vector_type(4))) float floatx4;  // MFMA C/D frag

__device__ __forceinline__ unsigned short f32_to_bf16_rne(float f) {
  union { float f; uint32_t u; } v; v.f = f;
  uint32_t u = v.u;
  uint32_t r = u + 0x7FFFu + ((u >> 16) & 1u);
  return (unsigned short)(r >> 16);
}
__device__ __forceinline__ float bf16_to_f32(unsigned short s) {
  union { uint32_t u; float f; } v; v.u = ((uint32_t)s) << 16;
  return v.f;
}

// ---------- expert_w [e][k][n] fp32 -> Wt [e][n][k] bf16 ----------
__global__ __launch_bounds__(256) void transpose_w_kernel(const float* __restrict__ w,
                                                          unsigned short* __restrict__ wt) {
  __shared__ float tile[32][33];
  int e = blockIdx.z;
  int n0 = blockIdx.x * 32, k0 = blockIdx.y * 32;
  int tx = threadIdx.x, ty = threadIdx.y;  // (32, 8)
  const float* wb = w + (size_t)e * H_DIM * H_DIM;
  unsigned short* wtb = wt + (size_t)e * H_DIM * H_DIM;
#pragma unroll
  for (int j = 0; j < 4; j++) {
    int r = ty + j * 8;
    tile[r][tx] = wb[(size_t)(k0 + r) * H_DIM + n0 + tx];
  }
  __syncthreads();
#pragma unroll
  for (int j = 0; j < 4; j++) {
    int r = ty + j * 8;
    wtb[(size_t)(n0 + r) * H_DIM + k0 + tx] = f32_to_bf16_rne(tile[tx][r]);
  }
}

// ---------- fused: x fp32 -> xb bf16, fp32 gate logits, top-2 softmax routing ----------
// grid 256 blocks x 256 thr; each wave handles 8 tokens. No atomics.
__global__ __launch_bounds__(256) void route_kernel(const float* __restrict__ x,
                                                    const float* __restrict__ gw,
                                                    unsigned short* __restrict__ xb,
                                                    int2* __restrict__ re,
                                                    float2* __restrict__ rw) {
  __shared__ float gws[E_NUM][1028];  // stride 1028 words: 16B-aligned rows, conflict-benign
  int tid = threadIdx.x;
  // stage gw [h][e] -> gws[e][h], vectorized
#pragma unroll
  for (int it = 0; it < 8; ++it) {
    int i4 = it * 256 + tid;          // float4 index, 0..2047
    float4 v = ((const float4*)gw)[i4];
    int h = i4 >> 1, e0 = (i4 & 1) * 4;
    gws[e0 + 0][h] = v.x;
    gws[e0 + 1][h] = v.y;
    gws[e0 + 2][h] = v.z;
    gws[e0 + 3][h] = v.w;
  }
  __syncthreads();
  int wid = tid >> 6, lane = tid & 63;
  for (int t = 0; t < 8; ++t) {
    int b = blockIdx.x * 32 + wid * 8 + t;
    const float4* xr = (const float4*)(x + (size_t)b * H_DIM);
    ushort4* xbr = (ushort4*)(xb + (size_t)b * H_DIM);
    float acc[E_NUM];
#pragma unroll
    for (int e = 0; e < E_NUM; e++) acc[e] = 0.f;
#pragma unroll
    for (int it = 0; it < 4; ++it) {
      int c4 = it * 64 + lane;  // float4 index within row
      float4 v = xr[c4];
      ushort4 o;
      o.x = f32_to_bf16_rne(v.x); o.y = f32_to_bf16_rne(v.y);
      o.z = f32_to_bf16_rne(v.z); o.w = f32_to_bf16_rne(v.w);
      xbr[c4] = o;
      int h = c4 * 4;
#pragma unroll
      for (int e = 0; e < E_NUM; e++) {
        float4 g = *(const float4*)&gws[e][h];  // ds_read_b128
        acc[e] += v.x * g.x + v.y * g.y + v.z * g.z + v.w * g.w;
      }
    }
#pragma unroll
    for (int e = 0; e < E_NUM; e++) {
#pragma unroll
      for (int off = 32; off; off >>= 1) acc[e] += __shfl_xor(acc[e], off, 64);
    }
    if (lane == 0) {
      int e0 = 0; float v0 = acc[0];
#pragma unroll
      for (int e = 1; e < E_NUM; e++) if (acc[e] > v0) { v0 = acc[e]; e0 = e; }
      int e1 = -1; float v1 = -1e30f;
#pragma unroll
      for (int e = 0; e < E_NUM; e++) if (e != e0 && acc[e] > v1) { v1 = acc[e]; e1 = e; }
      float s = expf(v1 - v0);
      float w0 = 1.0f / (1.0f + s);
      re[b] = make_int2(e0, e1);
      rw[b] = make_float2(w0, s * w0);
    }
  }
}

// ---------- deterministic compaction: 8 blocks (one per expert), ballot prefix ----------
__global__ __launch_bounds__(1024) void compact_kernel(const int2* __restrict__ re,
                                                       int* __restrict__ slot_tok,
                                                       int* __restrict__ yslot,
                                                       int* __restrict__ ebase,
                                                       int* __restrict__ ecnt) {
  __shared__ int wcnt[16];
  int e = blockIdx.x;
  int tid = threadIdx.x, wid = tid >> 6, lane = tid & 63;
  // pass 1: base[e] = total assignments with expert index < e
  int c = 0;
#pragma unroll
  for (int it = 0; it < 8; ++it) {
    int2 ee = re[it * 1024 + tid];
    c += (ee.x < e) + (ee.y < e);
  }
#pragma unroll
  for (int off = 32; off; off >>= 1) c += __shfl_xor(c, off, 64);
  if (lane == 0) wcnt[wid] = c;
  __syncthreads();
  int base = 0;
#pragma unroll
  for (int i = 0; i < 16; ++i) base += wcnt[i];
  __syncthreads();
  // pass 2: compact own expert (token-sorted)
  int run = 0;
  for (int it = 0; it < 8; ++it) {
    int t = it * 1024 + tid;
    int2 ee = re[t];
    bool f0 = (ee.x == e), f1 = (ee.y == e);
    bool f = f0 || f1;
    unsigned long long m = __ballot(f);
    int pre = __popcll(m & ((1ull << lane) - 1ull));
    if (lane == 0) wcnt[wid] = __popcll(m);
    __syncthreads();
    int wbase = 0, total = 0;
#pragma unroll
    for (int i = 0; i < 16; ++i) { int v = wcnt[i]; if (i < wid) wbase += v; total += v; }
    if (f) {
      int s = base + run + wbase + pre;
      slot_tok[s] = t;
      yslot[2 * t + (f0 ? 0 : 1)] = s;
    }
    run += total;
    __syncthreads();
  }
  if (tid == 0) { ebase[e] = base; ecnt[e] = run; }
}

// ---------- grouped gather-GEMM: y[slot] = x[tok] @ W_e  (bf16 out, no atomics) ----------
__device__ __forceinline__ void async_ld16(const void* g, void* l) {
  __builtin_amdgcn_global_load_lds((const __attribute__((address_space(1))) void*)g,
                                   (__attribute__((address_space(3))) void*)l, 16, 0, 0);
}

__global__ __launch_bounds__(256, 2) void moe_gemm_kernel(
    const unsigned short* __restrict__ xb,   // bf16 [B][H]
    const unsigned short* __restrict__ wt,   // bf16 [E][n][k]
    const int* __restrict__ ebase,
    const int* __restrict__ ecnt,
    const int* __restrict__ slot_tok,        // [NSLOT] global slots, token-sorted per expert
    unsigned short* __restrict__ y) {        // bf16 [NSLOT][H]
  int e = blockIdx.z;
  int c = ecnt[e];
  int m0 = blockIdx.y * 128;
  if (m0 >= c) return;
  int base = ebase[e];
  int n0 = blockIdx.x * 128;

  __shared__ __align__(16) unsigned short As[128 * 32];
  __shared__ __align__(16) unsigned short Bs[128 * 32];

  int tid = threadIdx.x, wid = tid >> 6, lane = tid & 63;
  int rs = wid * 16 + (lane >> 2);
  int kc = (lane & 3) * 8;
  const int* st = slot_tok + base;
  int ra1 = min(m0 + rs, c - 1);
  int ra2 = min(m0 + 64 + rs, c - 1);
  const unsigned short* gA1 = xb + (size_t)st[ra1] * H_DIM + kc;
  const unsigned short* gA2 = xb + (size_t)st[ra2] * H_DIM + kc;
  const unsigned short* gB1 = wt + ((size_t)e * H_DIM + n0 + rs) * H_DIM + kc;
  const unsigned short* gB2 = wt + ((size_t)e * H_DIM + n0 + 64 + rs) * H_DIM + kc;
  unsigned short* lA1 = As + wid * 512;
  unsigned short* lA2 = As + 2048 + wid * 512;
  unsigned short* lB1 = Bs + wid * 512;
  unsigned short* lB2 = Bs + 2048 + wid * 512;

  floatx4 acc[4][4];
#pragma unroll
  for (int a = 0; a < 4; ++a)
#pragma unroll
    for (int b = 0; b < 4; ++b)
#pragma unroll
      for (int q = 0; q < 4; ++q) acc[a][b][q] = 0.0f;

  int wm = (wid >> 1) * 64, wn = (wid & 1) * 64;
  int mr = lane & 15, kg = lane >> 4;

  for (int ks = 0; ks < H_DIM / 32; ++ks) {
    __syncthreads();
    async_ld16(gA1, lA1);
    async_ld16(gA2, lA2);
    async_ld16(gB1, lB1);
    async_ld16(gB2, lB2);
    gA1 += 32; gA2 += 32; gB1 += 32; gB2 += 32;
    __syncthreads();
    short8 af[4], bfr[4];
#pragma unroll
    for (int t = 0; t < 4; ++t) {
      af[t] = *(const short8*)(const void*)(As + (wm + t * 16 + mr) * 32 + kg * 8);
      bfr[t] = *(const short8*)(const void*)(Bs + (wn + t * 16 + mr) * 32 + kg * 8);
    }
#pragma unroll
    for (int tm = 0; tm < 4; ++tm)
#pragma unroll
      for (int tn = 0; tn < 4; ++tn)
        acc[tm][tn] = __builtin_amdgcn_mfma_f32_16x16x32_bf16(af[tm], bfr[tn], acc[tm][tn], 0, 0, 0);
  }

  // epilogue: y[base+r][n] = bf16(acc); C/D layout col=lane&15, row=kg*4+q
#pragma unroll
  for (int tm = 0; tm < 4; ++tm) {
#pragma unroll
    for (int q = 0; q < 4; ++q) {
      int r = m0 + wm + tm * 16 + kg * 4 + q;
      if (r < c) {
        unsigned short* yrow = y + (size_t)(base + r) * H_DIM + n0 + wn + mr;
#pragma unroll
        for (int tn = 0; tn < 4; ++tn) yrow[tn * 16] = f32_to_bf16_rne(acc[tm][tn][q]);
      }
    }
  }
}

// ---------- combine: out[t] = w0*y[s0] + w1*y[s1] ----------
__global__ __launch_bounds__(256) void combine_kernel(const unsigned short* __restrict__ y,
                                                      const int* __restrict__ yslot,
                                                      const float2* __restrict__ rw,
                                                      float* __restrict__ out) {
  int t = blockIdx.x;
  int s0 = yslot[2 * t], s1 = yslot[2 * t + 1];
  float2 w = rw[t];
  const ushort4* y0 = (const ushort4*)(y + (size_t)s0 * H_DIM);
  const ushort4* y1 = (const ushort4*)(y + (size_t)s1 * H_DIM);
  float4* o = (float4*)(out + (size_t)t * H_DIM);
  int i = threadIdx.x;  // 256 float4s per row
  ushort4 a = y0[i], b = y1[i];
  float4 r;
  r.x = w.x * bf16_to_f32(a.x) + w.y * bf16_to_f32(b.x);
  r.y = w.x * bf16_to_f32(a.y) + w.y * bf16_to_f32(b.y);
  r.z = w.x * bf16_to_f32(a.z) + w.y * bf16_to_f32(b.z);
  r.w = w.x * bf16_to_f32(a.w) + w.y * bf16_to_f32(b.w);
  o[i] = r;
}

extern "C" void kernel_launch(void* const* d_in, const int* in_sizes, int n_in,
                              void* d_out, int out_size, void* d_ws, size_t ws_size,
                              hipStream_t stream) {
  const float* x  = (const float*)d_in[0];   // [8192][1024]
  const float* gw = (const float*)d_in[1];   // [1024][8]
  const float* ew = (const float*)d_in[2];   // [8][1024][1024]
  float* out = (float*)d_out;                // [8192][1024]

  char* ws = (char*)d_ws;
  unsigned short* xb = (unsigned short*)ws;                               // 16 MiB
  unsigned short* wt = (unsigned short*)(ws + (size_t)16 * 1024 * 1024);  // 16 MiB
  unsigned short* y  = (unsigned short*)(ws + (size_t)32 * 1024 * 1024);  // 32 MiB
  char* p = ws + (size_t)64 * 1024 * 1024;
  int2*   re       = (int2*)p;                      // 64 KiB
  float2* rw       = (float2*)(p + (64 << 10));     // 64 KiB
  int*    slot_tok = (int*)(p + (128 << 10));       // 64 KiB
  int*    yslot    = (int*)(p + (192 << 10));       // 64 KiB
  int*    ebase    = (int*)(p + (256 << 10));
  int*    ecnt     = (int*)(p + (256 << 10) + 64);

  transpose_w_kernel<<<dim3(32, 32, E_NUM), dim3(32, 8), 0, stream>>>(ew, wt);
  route_kernel<<<256, 256, 0, stream>>>(x, gw, xb, re, rw);
  compact_kernel<<<E_NUM, 1024, 0, stream>>>(re, slot_tok, yslot, ebase, ecnt);
  moe_gemm_kernel<<<dim3(H_DIM / 128, B_TOK / 128, E_NUM), 256, 0, stream>>>(
      xb, wt, ebase, ecnt, slot_tok, y);
  combine_kernel<<<B_TOK, 256, 0, stream>>>(y, yslot, rw, out);
}

// Round 3
// 182.940 us; speedup vs baseline: 2.2412x; 1.0618x over previous
//
#include <hip/hip_runtime.h>
#include <hip/hip_bf16.h>
#include <stdint.h>

// Problem constants (B=8192, H=1024, E=8, K=2)
#define B_TOK 8192
#define H_DIM 1024
#define E_NUM 8
#define NSLOT (2 * B_TOK)

typedef __attribute__((ext_vector_type(8))) short short8;   // 8 bf16 = 4 VGPRs (MFMA A/B frag)
typedef __attribute__((ext_vector_type(4))) float floatx4;  // MFMA C/D frag

__device__ __forceinline__ unsigned short f32_to_bf16_rne(float f) {
  union { float f; uint32_t u; } v; v.f = f;
  uint32_t u = v.u;
  uint32_t r = u + 0x7FFFu + ((u >> 16) & 1u);
  return (unsigned short)(r >> 16);
}
__device__ __forceinline__ float bf16_to_f32(unsigned short s) {
  union { uint32_t u; float f; } v; v.u = ((uint32_t)s) << 16;
  return v.f;
}

// ---------- expert_w [e][k][n] fp32 -> Wt [e][n][k] bf16; 64x64 tiles, ushort4 stores ----------
__global__ __launch_bounds__(256) void transpose_w_kernel(const float* __restrict__ w,
                                                          unsigned short* __restrict__ wt) {
  __shared__ float tile[64][68];
  int e = blockIdx.z;
  int k0 = blockIdx.y * 64, n0 = blockIdx.x * 64;
  const float* wb = w + ((size_t)e * H_DIM + k0) * H_DIM + n0;
  unsigned short* wtb = wt + ((size_t)e * H_DIM + n0) * H_DIM + k0;
  int t = threadIdx.x;
  int rr = t >> 4, c4 = t & 15;
#pragma unroll
  for (int j = 0; j < 4; ++j) {
    int r = rr + j * 16;
    float4 v = *(const float4*)(wb + (size_t)r * H_DIM + c4 * 4);
    *(float4*)&tile[r][c4 * 4] = v;
  }
  __syncthreads();
#pragma unroll
  for (int j = 0; j < 4; ++j) {
    int nr = rr + j * 16;
    ushort4 o;
    o.x = f32_to_bf16_rne(tile[c4 * 4 + 0][nr]);
    o.y = f32_to_bf16_rne(tile[c4 * 4 + 1][nr]);
    o.z = f32_to_bf16_rne(tile[c4 * 4 + 2][nr]);
    o.w = f32_to_bf16_rne(tile[c4 * 4 + 3][nr]);
    *(ushort4*)(wtb + (size_t)nr * H_DIM + c4 * 4) = o;
  }
}

// ---------- fused: x fp32 -> xb bf16, fp32 gate logits, top-2 softmax routing ----------
// 512 blocks x 256 thr; each wave handles 4 tokens. No atomics.
__global__ __launch_bounds__(256) void route_kernel(const float* __restrict__ x,
                                                    const float* __restrict__ gw,
                                                    unsigned short* __restrict__ xb,
                                                    int2* __restrict__ re,
                                                    float2* __restrict__ rw) {
  __shared__ float gws[E_NUM][1028];
  int tid = threadIdx.x;
#pragma unroll
  for (int it = 0; it < 8; ++it) {
    int i4 = it * 256 + tid;
    float4 v = ((const float4*)gw)[i4];
    int h = i4 >> 1, e0 = (i4 & 1) * 4;
    gws[e0 + 0][h] = v.x;
    gws[e0 + 1][h] = v.y;
    gws[e0 + 2][h] = v.z;
    gws[e0 + 3][h] = v.w;
  }
  __syncthreads();
  int wid = tid >> 6, lane = tid & 63;
  for (int t = 0; t < 4; ++t) {
    int b = blockIdx.x * 16 + wid * 4 + t;
    const float4* xr = (const float4*)(x + (size_t)b * H_DIM);
    ushort4* xbr = (ushort4*)(xb + (size_t)b * H_DIM);
    float acc[E_NUM];
#pragma unroll
    for (int e = 0; e < E_NUM; e++) acc[e] = 0.f;
#pragma unroll
    for (int it = 0; it < 4; ++it) {
      int c4 = it * 64 + lane;
      float4 v = xr[c4];
      ushort4 o;
      o.x = f32_to_bf16_rne(v.x); o.y = f32_to_bf16_rne(v.y);
      o.z = f32_to_bf16_rne(v.z); o.w = f32_to_bf16_rne(v.w);
      xbr[c4] = o;
      int h = c4 * 4;
#pragma unroll
      for (int e = 0; e < E_NUM; e++) {
        float4 g = *(const float4*)&gws[e][h];
        acc[e] += v.x * g.x + v.y * g.y + v.z * g.z + v.w * g.w;
      }
    }
#pragma unroll
    for (int e = 0; e < E_NUM; e++) {
#pragma unroll
      for (int off = 32; off; off >>= 1) acc[e] += __shfl_xor(acc[e], off, 64);
    }
    if (lane == 0) {
      int e0 = 0; float v0 = acc[0];
#pragma unroll
      for (int e = 1; e < E_NUM; e++) if (acc[e] > v0) { v0 = acc[e]; e0 = e; }
      int e1 = -1; float v1 = -1e30f;
#pragma unroll
      for (int e = 0; e < E_NUM; e++) if (e != e0 && acc[e] > v1) { v1 = acc[e]; e1 = e; }
      float s = expf(v1 - v0);
      float w0 = 1.0f / (1.0f + s);
      re[b] = make_int2(e0, e1);
      rw[b] = make_float2(w0, s * w0);
    }
  }
}

// ---------- deterministic compaction: 8 blocks, single __syncthreads ----------
__global__ __launch_bounds__(1024) void compact_kernel(const int2* __restrict__ re,
                                                       int* __restrict__ slot_tok,
                                                       int* __restrict__ yslot,
                                                       int* __restrict__ ebase,
                                                       int* __restrict__ ecnt) {
  __shared__ int wcnt[8][16];  // per-iter per-wave own-expert counts
  __shared__ int bless[16];    // per-wave counts of experts < e
  int e = blockIdx.x;
  int tid = threadIdx.x, wid = tid >> 6, lane = tid & 63;
  int cless = 0;
  int flag[8];
  unsigned long long mm[8];
#pragma unroll
  for (int it = 0; it < 8; ++it) {
    int2 ee = re[it * 1024 + tid];
    cless += (ee.x < e) + (ee.y < e);
    bool f0 = (ee.x == e), f1 = (ee.y == e);
    flag[it] = f0 ? 1 : (f1 ? 2 : 0);
    mm[it] = __ballot(f0 || f1);
    if (lane == 0) wcnt[it][wid] = __popcll(mm[it]);
  }
#pragma unroll
  for (int off = 32; off; off >>= 1) cless += __shfl_xor(cless, off, 64);
  if (lane == 0) bless[wid] = cless;
  __syncthreads();
  int base = 0;
#pragma unroll
  for (int i = 0; i < 16; ++i) base += bless[i];
  int run = 0;
#pragma unroll
  for (int it = 0; it < 8; ++it) {
    int wbase = 0, total = 0;
#pragma unroll
    for (int i = 0; i < 16; ++i) { int v = wcnt[it][i]; if (i < wid) wbase += v; total += v; }
    if (flag[it]) {
      int pre = __popcll(mm[it] & ((1ull << lane) - 1ull));
      int s = base + run + wbase + pre;
      int t = it * 1024 + tid;
      slot_tok[s] = t;
      yslot[2 * t + (flag[it] == 1 ? 0 : 1)] = s;
    }
    run += total;
  }
  if (tid == 0) { ebase[e] = base; ecnt[e] = run; }
}

// ---------- grouped gather-GEMM: y[slot] = x[tok] @ W_e  (bf16 out, no atomics) ----------
// XOR chunk swizzle kills the 8-way ds_read_b128 bank conflict; XCD-grouped grid for A reuse.
__device__ __forceinline__ void async_ld16(const void* g, void* l) {
  __builtin_amdgcn_global_load_lds((const __attribute__((address_space(1))) void*)g,
                                   (__attribute__((address_space(3))) void*)l, 16, 0, 0);
}

__global__ __launch_bounds__(256, 4) void moe_gemm_kernel(
    const unsigned short* __restrict__ xb,   // bf16 [B][H]
    const unsigned short* __restrict__ wt,   // bf16 [E][n][k]
    const int* __restrict__ ebase,
    const int* __restrict__ ecnt,
    const int* __restrict__ slot_tok,        // token-sorted slots per expert
    unsigned short* __restrict__ y) {        // bf16 [NSLOT][H]
  int e = blockIdx.z;
  int c = ecnt[e];
  // XCD swizzle: linear%8 == blockIdx.x == m_lo, so all 8 N-blocks of an M-tile
  // land on one XCD -> A rows fetched once per XCD.
  int m_idx = ((blockIdx.y >> 3) << 3) + blockIdx.x;
  int n_idx = blockIdx.y & 7;
  int m0 = m_idx * 128;
  if (m0 >= c) return;
  int base = ebase[e];
  int n0 = n_idx * 128;

  __shared__ __align__(16) unsigned short As[128 * 32];
  __shared__ __align__(16) unsigned short Bs[128 * 32];

  int tid = threadIdx.x, wid = tid >> 6, lane = tid & 63;
  int rs = wid * 16 + (lane >> 2);        // staged row 0..63 (and +64)
  int swz = (rs >> 1) & 3;                // XOR swizzle selector (same for rs and rs+64)
  int kc = ((lane & 3) ^ swz) * 8;        // global bf16 chunk -> fixed LDS chunk lane&3
  const int* st = slot_tok + base;
  int ra1 = min(m0 + rs, c - 1);
  int ra2 = min(m0 + 64 + rs, c - 1);
  const unsigned short* gA1 = xb + (size_t)st[ra1] * H_DIM + kc;
  const unsigned short* gA2 = xb + (size_t)st[ra2] * H_DIM + kc;
  const unsigned short* gB1 = wt + ((size_t)e * H_DIM + n0 + rs) * H_DIM + kc;
  const unsigned short* gB2 = wt + ((size_t)e * H_DIM + n0 + 64 + rs) * H_DIM + kc;
  unsigned short* lA1 = As + wid * 512;
  unsigned short* lA2 = As + 2048 + wid * 512;
  unsigned short* lB1 = Bs + wid * 512;
  unsigned short* lB2 = Bs + 2048 + wid * 512;

  floatx4 acc[4][4];
#pragma unroll
  for (int a = 0; a < 4; ++a)
#pragma unroll
    for (int b = 0; b < 4; ++b)
#pragma unroll
      for (int q = 0; q < 4; ++q) acc[a][b][q] = 0.0f;

  int wm = (wid >> 1) * 64, wn = (wid & 1) * 64;
  int mr = lane & 15, kg = lane >> 4;

  for (int ks = 0; ks < H_DIM / 32; ++ks) {
    __syncthreads();
    async_ld16(gA1, lA1);
    async_ld16(gA2, lA2);
    async_ld16(gB1, lB1);
    async_ld16(gB2, lB2);
    gA1 += 32; gA2 += 32; gB1 += 32; gB2 += 32;
    __syncthreads();
    short8 af[4], bfr[4];
#pragma unroll
    for (int t = 0; t < 4; ++t) {
      int rowa = wm + t * 16 + mr;
      int rowb = wn + t * 16 + mr;
      af[t]  = *(const short8*)(const void*)(As + rowa * 32 + ((kg ^ ((rowa >> 1) & 3)) * 8));
      bfr[t] = *(const short8*)(const void*)(Bs + rowb * 32 + ((kg ^ ((rowb >> 1) & 3)) * 8));
    }
#pragma unroll
    for (int tm = 0; tm < 4; ++tm)
#pragma unroll
      for (int tn = 0; tn < 4; ++tn)
        acc[tm][tn] = __builtin_amdgcn_mfma_f32_16x16x32_bf16(af[tm], bfr[tn], acc[tm][tn], 0, 0, 0);
  }

  // epilogue: y[base+r][n] = bf16(acc); C/D layout col=lane&15, row=kg*4+q
#pragma unroll
  for (int tm = 0; tm < 4; ++tm) {
#pragma unroll
    for (int q = 0; q < 4; ++q) {
      int r = m0 + wm + tm * 16 + kg * 4 + q;
      if (r < c) {
        unsigned short* yrow = y + (size_t)(base + r) * H_DIM + n0 + wn + mr;
#pragma unroll
        for (int tn = 0; tn < 4; ++tn) yrow[tn * 16] = f32_to_bf16_rne(acc[tm][tn][q]);
      }
    }
  }
}

// ---------- combine: out[t] = w0*y[s0] + w1*y[s1] ----------
__global__ __launch_bounds__(256) void combine_kernel(const unsigned short* __restrict__ y,
                                                      const int* __restrict__ yslot,
                                                      const float2* __restrict__ rw,
                                                      float* __restrict__ out) {
  int t = blockIdx.x;
  int s0 = yslot[2 * t], s1 = yslot[2 * t + 1];
  float2 w = rw[t];
  const ushort4* y0 = (const ushort4*)(y + (size_t)s0 * H_DIM);
  const ushort4* y1 = (const ushort4*)(y + (size_t)s1 * H_DIM);
  float4* o = (float4*)(out + (size_t)t * H_DIM);
  int i = threadIdx.x;
  ushort4 a = y0[i], b = y1[i];
  float4 r;
  r.x = w.x * bf16_to_f32(a.x) + w.y * bf16_to_f32(b.x);
  r.y = w.x * bf16_to_f32(a.y) + w.y * bf16_to_f32(b.y);
  r.z = w.x * bf16_to_f32(a.z) + w.y * bf16_to_f32(b.z);
  r.w = w.x * bf16_to_f32(a.w) + w.y * bf16_to_f32(b.w);
  o[i] = r;
}

extern "C" void kernel_launch(void* const* d_in, const int* in_sizes, int n_in,
                              void* d_out, int out_size, void* d_ws, size_t ws_size,
                              hipStream_t stream) {
  const float* x  = (const float*)d_in[0];   // [8192][1024]
  const float* gw = (const float*)d_in[1];   // [1024][8]
  const float* ew = (const float*)d_in[2];   // [8][1024][1024]
  float* out = (float*)d_out;                // [8192][1024]

  char* ws = (char*)d_ws;
  unsigned short* xb = (unsigned short*)ws;                               // 16 MiB
  unsigned short* wt = (unsigned short*)(ws + (size_t)16 * 1024 * 1024);  // 16 MiB
  unsigned short* y  = (unsigned short*)(ws + (size_t)32 * 1024 * 1024);  // 32 MiB
  char* p = ws + (size_t)64 * 1024 * 1024;
  int2*   re       = (int2*)p;                      // 64 KiB
  float2* rw       = (float2*)(p + (64 << 10));     // 64 KiB
  int*    slot_tok = (int*)(p + (128 << 10));       // 64 KiB
  int*    yslot    = (int*)(p + (192 << 10));       // 64 KiB
  int*    ebase    = (int*)(p + (256 << 10));
  int*    ecnt     = (int*)(p + (256 << 10) + 64);

  transpose_w_kernel<<<dim3(16, 16, E_NUM), 256, 0, stream>>>(ew, wt);
  route_kernel<<<512, 256, 0, stream>>>(x, gw, xb, re, rw);
  compact_kernel<<<E_NUM, 1024, 0, stream>>>(re, slot_tok, yslot, ebase, ecnt);
  moe_gemm_kernel<<<dim3(8, 64, E_NUM), 256, 0, stream>>>(
      xb, wt, ebase, ecnt, slot_tok, y);
  combine_kernel<<<B_TOK, 256, 0, stream>>>(y, yslot, rw, out);
}

// Round 4
// 170.452 us; speedup vs baseline: 2.4054x; 1.0733x over previous
//
#include <hip/hip_runtime.h>
#include <hip/hip_bf16.h>
#include <stdint.h>

// Problem constants (B=8192, H=1024, E=8, K=2)
#define B_TOK 8192
#define H_DIM 1024
#define E_NUM 8
#define NSLOT (2 * B_TOK)

typedef __attribute__((ext_vector_type(8))) short short8;   // 8 bf16 = 4 VGPRs (MFMA A/B frag)
typedef __attribute__((ext_vector_type(4))) float floatx4;  // MFMA C/D frag

__device__ __forceinline__ unsigned short f32_to_bf16_rne(float f) {
  union { float f; uint32_t u; } v; v.f = f;
  uint32_t u = v.u;
  uint32_t r = u + 0x7FFFu + ((u >> 16) & 1u);
  return (unsigned short)(r >> 16);
}
__device__ __forceinline__ float bf16_to_f32(unsigned short s) {
  union { uint32_t u; float f; } v; v.u = ((uint32_t)s) << 16;
  return v.f;
}

// ---------- fused prologue: [0,2048) transpose expert_w -> Wt bf16 ; [2048,2560) route ----------
__global__ __launch_bounds__(256) void prep_kernel(const float* __restrict__ x,
                                                   const float* __restrict__ gw,
                                                   const float* __restrict__ ew,
                                                   unsigned short* __restrict__ xb,
                                                   unsigned short* __restrict__ wt,
                                                   int2* __restrict__ re,
                                                   float2* __restrict__ rw) {
  __shared__ float smem[E_NUM * 1028];  // 32.9 KB, reused by both halves
  int bid = blockIdx.x;
  int tid = threadIdx.x;
  if (bid < 2048) {
    // ---- transpose 64x64 tile: w[e][k][n] fp32 -> wt[e][n][k] bf16 ----
    float (*tile)[65] = (float(*)[65])smem;  // [n][k], +1 pad
    int e = bid >> 8;
    int n0 = ((bid >> 4) & 15) * 64, k0 = (bid & 15) * 64;
    const float* wb = ew + ((size_t)e * H_DIM + k0) * H_DIM + n0;
    unsigned short* wtb = wt + ((size_t)e * H_DIM + n0) * H_DIM + k0;
    int rr = tid >> 4, c4 = tid & 15;
#pragma unroll
    for (int j = 0; j < 4; ++j) {
      int r = rr + j * 16;  // k-row in tile
      float4 v = *(const float4*)(wb + (size_t)r * H_DIM + c4 * 4);
      tile[c4 * 4 + 0][r] = v.x;  // scalar transposed writes: bank=(4c4+i+r)%32 -> 2-way, free
      tile[c4 * 4 + 1][r] = v.y;
      tile[c4 * 4 + 2][r] = v.z;
      tile[c4 * 4 + 3][r] = v.w;
    }
    __syncthreads();
#pragma unroll
    for (int j = 0; j < 4; ++j) {
      int nr = rr + j * 16;  // n-row in tile
      float4 v = *(const float4*)&tile[nr][c4 * 4];
      ushort4 o;
      o.x = f32_to_bf16_rne(v.x); o.y = f32_to_bf16_rne(v.y);
      o.z = f32_to_bf16_rne(v.z); o.w = f32_to_bf16_rne(v.w);
      *(ushort4*)(wtb + (size_t)nr * H_DIM + c4 * 4) = o;
    }
  } else {
    // ---- route: x fp32 -> xb bf16 + fp32 gate logits + top-2 softmax ----
    int rb = bid - 2048;  // 0..511
    float (*gws)[1028] = (float(*)[1028])smem;
#pragma unroll
    for (int it = 0; it < 8; ++it) {
      int i4 = it * 256 + tid;
      float4 v = ((const float4*)gw)[i4];
      int h = i4 >> 1, e0 = (i4 & 1) * 4;
      gws[e0 + 0][h] = v.x;
      gws[e0 + 1][h] = v.y;
      gws[e0 + 2][h] = v.z;
      gws[e0 + 3][h] = v.w;
    }
    __syncthreads();
    int wid = tid >> 6, lane = tid & 63;
    for (int t = 0; t < 4; ++t) {
      int b = rb * 16 + wid * 4 + t;
      const float4* xr = (const float4*)(x + (size_t)b * H_DIM);
      ushort4* xbr = (ushort4*)(xb + (size_t)b * H_DIM);
      float acc[E_NUM];
#pragma unroll
      for (int e = 0; e < E_NUM; e++) acc[e] = 0.f;
#pragma unroll
      for (int it = 0; it < 4; ++it) {
        int c4 = it * 64 + lane;
        float4 v = xr[c4];
        ushort4 o;
        o.x = f32_to_bf16_rne(v.x); o.y = f32_to_bf16_rne(v.y);
        o.z = f32_to_bf16_rne(v.z); o.w = f32_to_bf16_rne(v.w);
        xbr[c4] = o;
        int h = c4 * 4;
#pragma unroll
        for (int e = 0; e < E_NUM; e++) {
          float4 g = *(const float4*)&gws[e][h];
          acc[e] += v.x * g.x + v.y * g.y + v.z * g.z + v.w * g.w;
        }
      }
#pragma unroll
      for (int e = 0; e < E_NUM; e++) {
#pragma unroll
        for (int off = 32; off; off >>= 1) acc[e] += __shfl_xor(acc[e], off, 64);
      }
      if (lane == 0) {
        int e0 = 0; float v0 = acc[0];
#pragma unroll
        for (int e = 1; e < E_NUM; e++) if (acc[e] > v0) { v0 = acc[e]; e0 = e; }
        int e1 = -1; float v1 = -1e30f;
#pragma unroll
        for (int e = 0; e < E_NUM; e++) if (e != e0 && acc[e] > v1) { v1 = acc[e]; e1 = e; }
        float s = expf(v1 - v0);
        float w0 = 1.0f / (1.0f + s);
        re[b] = make_int2(e0, e1);
        rw[b] = make_float2(w0, s * w0);
      }
    }
  }
}

// ---------- deterministic compaction: 8 blocks, single __syncthreads ----------
__global__ __launch_bounds__(1024) void compact_kernel(const int2* __restrict__ re,
                                                       int* __restrict__ slot_tok,
                                                       int* __restrict__ yslot,
                                                       int* __restrict__ ebase,
                                                       int* __restrict__ ecnt) {
  __shared__ int wcnt[8][16];
  __shared__ int bless[16];
  int e = blockIdx.x;
  int tid = threadIdx.x, wid = tid >> 6, lane = tid & 63;
  int cless = 0;
  int flag[8];
  unsigned long long mm[8];
#pragma unroll
  for (int it = 0; it < 8; ++it) {
    int2 ee = re[it * 1024 + tid];
    cless += (ee.x < e) + (ee.y < e);
    bool f0 = (ee.x == e), f1 = (ee.y == e);
    flag[it] = f0 ? 1 : (f1 ? 2 : 0);
    mm[it] = __ballot(f0 || f1);
    if (lane == 0) wcnt[it][wid] = __popcll(mm[it]);
  }
#pragma unroll
  for (int off = 32; off; off >>= 1) cless += __shfl_xor(cless, off, 64);
  if (lane == 0) bless[wid] = cless;
  __syncthreads();
  int base = 0;
#pragma unroll
  for (int i = 0; i < 16; ++i) base += bless[i];
  int run = 0;
#pragma unroll
  for (int it = 0; it < 8; ++it) {
    int wbase = 0, total = 0;
#pragma unroll
    for (int i = 0; i < 16; ++i) { int v = wcnt[it][i]; if (i < wid) wbase += v; total += v; }
    if (flag[it]) {
      int pre = __popcll(mm[it] & ((1ull << lane) - 1ull));
      int s = base + run + wbase + pre;
      int t = it * 1024 + tid;
      slot_tok[s] = t;
      yslot[2 * t + (flag[it] == 1 ? 0 : 1)] = s;
    }
    run += total;
  }
  if (tid == 0) { ebase[e] = base; ecnt[e] = run; }
}

// ---------- grouped gather-GEMM, BK=64: y[slot] = x[tok] @ W_e (bf16 out) ----------
__device__ __forceinline__ void async_ld16(const void* g, void* l) {
  __builtin_amdgcn_global_load_lds((const __attribute__((address_space(1))) void*)g,
                                   (__attribute__((address_space(3))) void*)l, 16, 0, 0);
}

__global__ __launch_bounds__(256, 3) void moe_gemm_kernel(
    const unsigned short* __restrict__ xb,   // bf16 [B][H]
    const unsigned short* __restrict__ wt,   // bf16 [E][n][k]
    const int* __restrict__ ebase,
    const int* __restrict__ ecnt,
    const int* __restrict__ slot_tok,
    unsigned short* __restrict__ y) {        // bf16 [NSLOT][H]
  int e = blockIdx.z;
  int c = ecnt[e];
  int m_idx = ((blockIdx.y >> 3) << 3) + blockIdx.x;  // XCD swizzle: all n of an m-tile on one XCD
  int n_idx = blockIdx.y & 7;
  int m0 = m_idx * 128;
  if (m0 >= c) return;
  int base = ebase[e];
  int n0 = n_idx * 128;

  __shared__ __align__(16) unsigned short As[128 * 64];  // 16 KB, rows of 128 B (8 chunks)
  __shared__ __align__(16) unsigned short Bs[128 * 64];  // 16 KB

  int tid = threadIdx.x, wid = tid >> 6, lane = tid & 63;
  int rloc = lane >> 3;   // 0..7 within 8-row group
  int cl = lane & 7;      // 16B chunk slot in LDS row
  const int* st = slot_tok + base;

  const unsigned short* gA[4];
  const unsigned short* gB[4];
  unsigned short* lA[4];
  unsigned short* lB[4];
#pragma unroll
  for (int j = 0; j < 4; ++j) {
    int rl = wid * 32 + j * 8 + rloc;          // tile row 0..127
    int g = (cl ^ (rl & 7)) * 8;               // swizzled global chunk -> LDS chunk cl
    int ra = min(m0 + rl, c - 1);
    gA[j] = xb + (size_t)st[ra] * H_DIM + g;
    gB[j] = wt + ((size_t)e * H_DIM + n0 + rl) * H_DIM + g;
    lA[j] = As + (wid * 32 + j * 8) * 64;      // wave-uniform base; lane lands at +lane*16B
    lB[j] = Bs + (wid * 32 + j * 8) * 64;
  }

  floatx4 acc[4][4];
#pragma unroll
  for (int a = 0; a < 4; ++a)
#pragma unroll
    for (int b = 0; b < 4; ++b)
#pragma unroll
      for (int q = 0; q < 4; ++q) acc[a][b][q] = 0.0f;

  int wm = (wid >> 1) * 64, wn = (wid & 1) * 64;
  int mr = lane & 15, kg = lane >> 4;
  int sw = mr & 7;  // reader swizzle (rows wm+t*16+mr have row&7 == mr&7)

  for (int ks = 0; ks < 16; ++ks) {
    __syncthreads();
#pragma unroll
    for (int j = 0; j < 4; ++j) {
      async_ld16(gA[j], lA[j]);
      async_ld16(gB[j], lB[j]);
    }
#pragma unroll
    for (int j = 0; j < 4; ++j) { gA[j] += 64; gB[j] += 64; }
    __syncthreads();
#pragma unroll
    for (int kk = 0; kk < 2; ++kk) {
      int cb = ((kk * 4 + kg) ^ sw) * 8;  // swizzled LDS bf16 offset for this frag
      short8 af[4], bfr[4];
#pragma unroll
      for (int t = 0; t < 4; ++t) {
        af[t]  = *(const short8*)(const void*)(As + (wm + t * 16 + mr) * 64 + cb);
        bfr[t] = *(const short8*)(const void*)(Bs + (wn + t * 16 + mr) * 64 + cb);
      }
#pragma unroll
      for (int tm = 0; tm < 4; ++tm)
#pragma unroll
        for (int tn = 0; tn < 4; ++tn)
          acc[tm][tn] = __builtin_amdgcn_mfma_f32_16x16x32_bf16(af[tm], bfr[tn], acc[tm][tn], 0, 0, 0);
    }
  }

  // epilogue: y[base+r][n] = bf16(acc); C/D layout col=lane&15, row=kg*4+q
#pragma unroll
  for (int tm = 0; tm < 4; ++tm) {
#pragma unroll
    for (int q = 0; q < 4; ++q) {
      int r = m0 + wm + tm * 16 + kg * 4 + q;
      if (r < c) {
        unsigned short* yrow = y + (size_t)(base + r) * H_DIM + n0 + wn + mr;
#pragma unroll
        for (int tn = 0; tn < 4; ++tn) yrow[tn * 16] = f32_to_bf16_rne(acc[tm][tn][q]);
      }
    }
  }
}

// ---------- combine: out[t] = w0*y[s0] + w1*y[s1]; 4 tokens/block, 4 f4/lane ----------
__global__ __launch_bounds__(256) void combine_kernel(const unsigned short* __restrict__ y,
                                                      const int* __restrict__ yslot,
                                                      const float2* __restrict__ rw,
                                                      float* __restrict__ out) {
  int wid = threadIdx.x >> 6, lane = threadIdx.x & 63;
  int t = blockIdx.x * 4 + wid;
  int s0 = yslot[2 * t], s1 = yslot[2 * t + 1];
  float2 w = rw[t];
  const ushort4* y0 = (const ushort4*)(y + (size_t)s0 * H_DIM);
  const ushort4* y1 = (const ushort4*)(y + (size_t)s1 * H_DIM);
  float4* o = (float4*)(out + (size_t)t * H_DIM);
  ushort4 a[4], b[4];
#pragma unroll
  for (int j = 0; j < 4; ++j) {
    int i = j * 64 + lane;
    a[j] = y0[i];
    b[j] = y1[i];
  }
#pragma unroll
  for (int j = 0; j < 4; ++j) {
    int i = j * 64 + lane;
    float4 r;
    r.x = w.x * bf16_to_f32(a[j].x) + w.y * bf16_to_f32(b[j].x);
    r.y = w.x * bf16_to_f32(a[j].y) + w.y * bf16_to_f32(b[j].y);
    r.z = w.x * bf16_to_f32(a[j].z) + w.y * bf16_to_f32(b[j].z);
    r.w = w.x * bf16_to_f32(a[j].w) + w.y * bf16_to_f32(b[j].w);
    o[i] = r;
  }
}

extern "C" void kernel_launch(void* const* d_in, const int* in_sizes, int n_in,
                              void* d_out, int out_size, void* d_ws, size_t ws_size,
                              hipStream_t stream) {
  const float* x  = (const float*)d_in[0];   // [8192][1024]
  const float* gw = (const float*)d_in[1];   // [1024][8]
  const float* ew = (const float*)d_in[2];   // [8][1024][1024]
  float* out = (float*)d_out;                // [8192][1024]

  char* ws = (char*)d_ws;
  unsigned short* xb = (unsigned short*)ws;                               // 16 MiB
  unsigned short* wt = (unsigned short*)(ws + (size_t)16 * 1024 * 1024);  // 16 MiB
  unsigned short* y  = (unsigned short*)(ws + (size_t)32 * 1024 * 1024);  // 32 MiB
  char* p = ws + (size_t)64 * 1024 * 1024;
  int2*   re       = (int2*)p;                      // 64 KiB
  float2* rw       = (float2*)(p + (64 << 10));     // 64 KiB
  int*    slot_tok = (int*)(p + (128 << 10));       // 64 KiB
  int*    yslot    = (int*)(p + (192 << 10));       // 64 KiB
  int*    ebase    = (int*)(p + (256 << 10));
  int*    ecnt     = (int*)(p + (256 << 10) + 64);

  prep_kernel<<<2560, 256, 0, stream>>>(x, gw, ew, xb, wt, re, rw);
  compact_kernel<<<E_NUM, 1024, 0, stream>>>(re, slot_tok, yslot, ebase, ecnt);
  moe_gemm_kernel<<<dim3(8, 64, E_NUM), 256, 0, stream>>>(
      xb, wt, ebase, ecnt, slot_tok, y);
  combine_kernel<<<B_TOK / 4, 256, 0, stream>>>(y, yslot, rw, out);
}